// Round 5
// baseline (14306.540 us; speedup 1.0000x reference)
//
#include <hip/hip_runtime.h>
#include <math.h>

#define Vz 10000
#define Bz 32
#define Tz 512
#define Hz 512
#define Pz 20
#define NBLK 128

typedef unsigned short u16;
typedef __attribute__((ext_vector_type(8)))  short bf16x8_t;   // 8 bf16 = 4 VGPR
typedef __attribute__((ext_vector_type(8)))  unsigned short u16x8;
typedef __attribute__((ext_vector_type(16))) float f32x16_t;   // 32x32 acc frag

__device__ __forceinline__ float sigf(float x) { return 1.0f / (1.0f + expf(-x)); }

__device__ __forceinline__ u16 f2bf(float x) {           // round-to-nearest-even
    unsigned u = __float_as_uint(x);
    u += 0x7fff + ((u >> 16) & 1);
    return (u16)(u >> 16);
}
__device__ __forceinline__ float bf2f(u16 h) {
    return __uint_as_float(((unsigned)h) << 16);
}

__device__ __forceinline__ void gload16(const u16* g, const u16* l) {
    __builtin_amdgcn_global_load_lds(
        (const __attribute__((address_space(1))) void*)g,
        (__attribute__((address_space(3))) void*)l, 16, 0, 0);
}

// ---------------------------------------------------------------- splitters
__global__ __launch_bounds__(256) void split_k(const float* __restrict__ src,
                                               u16* __restrict__ dH, u16* __restrict__ dL,
                                               int total4, int srcW4, int dstStride, int colOff) {
    int i = blockIdx.x * 256 + threadIdx.x;
    if (i >= total4) return;
    int row = i / srcW4;
    int c4 = (i - row * srcW4) << 2;
    float4 v = *(const float4*)(src + (size_t)row * ((size_t)srcW4 << 2) + c4);
    ushort4 H, L;
    H.x = f2bf(v.x); L.x = f2bf(v.x - bf2f(H.x));
    H.y = f2bf(v.y); L.y = f2bf(v.y - bf2f(H.y));
    H.z = f2bf(v.z); L.z = f2bf(v.z - bf2f(H.z));
    H.w = f2bf(v.w); L.w = f2bf(v.w - bf2f(H.w));
    size_t d = (size_t)row * dstStride + colOff + c4;
    *(ushort4*)(dH + d) = H;
    *(ushort4*)(dL + d) = L;
}

__global__ __launch_bounds__(256) void embed_split_k(const int* __restrict__ inp,
                                                     const float* __restrict__ etab,
                                                     u16* __restrict__ dH, u16* __restrict__ dL) {
    int i = blockIdx.x * 256 + threadIdx.x;
    int row = i >> 7;
    int c4 = (i & 127) << 2;
    float4 v = *(const float4*)(etab + (size_t)inp[row] * Hz + c4);
    ushort4 H, L;
    H.x = f2bf(v.x); L.x = f2bf(v.x - bf2f(H.x));
    H.y = f2bf(v.y); L.y = f2bf(v.y - bf2f(H.y));
    H.z = f2bf(v.z); L.z = f2bf(v.z - bf2f(H.z));
    H.w = f2bf(v.w); L.w = f2bf(v.w - bf2f(H.w));
    size_t d = (size_t)row * Hz + c4;
    *(ushort4*)(dH + d) = H;
    *(ushort4*)(dL + d) = L;
}

// per-batch transpose + split: enc[b][t][h] -> encT H/L [b][h][t]
__global__ __launch_bounds__(256) void tsplit_k(const float* __restrict__ enc,
                                                u16* __restrict__ dH, u16* __restrict__ dL) {
    __shared__ float ls[64][65];
    const int b = blockIdx.z;
    const int t0 = blockIdx.y * 64;
    const int h0 = blockIdx.x * 64;
    const int tid = threadIdx.x;
    const int rr = tid >> 4;
    const int cc = (tid & 15) << 2;
    const float* eb = enc + (size_t)b * Tz * Hz;
#pragma unroll
    for (int i = 0; i < 4; ++i) {
        int t = rr + i * 16;
        float4 v = *(const float4*)(eb + (size_t)(t0 + t) * Hz + h0 + cc);
        ls[t][cc] = v.x; ls[t][cc + 1] = v.y; ls[t][cc + 2] = v.z; ls[t][cc + 3] = v.w;
    }
    __syncthreads();
    u16* oH = dH + (size_t)b * Tz * Hz;
    u16* oL = dL + (size_t)b * Tz * Hz;
#pragma unroll
    for (int i = 0; i < 4; ++i) {
        int h = rr + i * 16;
        float x0 = ls[cc + 0][h], x1 = ls[cc + 1][h], x2 = ls[cc + 2][h], x3 = ls[cc + 3][h];
        ushort4 H, L;
        H.x = f2bf(x0); L.x = f2bf(x0 - bf2f(H.x));
        H.y = f2bf(x1); L.y = f2bf(x1 - bf2f(H.y));
        H.z = f2bf(x2); L.z = f2bf(x2 - bf2f(H.z));
        H.w = f2bf(x3); L.w = f2bf(x3 - bf2f(H.w));
        size_t d = (size_t)(h0 + h) * Tz + t0 + cc;
        *(ushort4*)(oH + d) = H;
        *(ushort4*)(oL + d) = L;
    }
}

// ------------------------------------------------------------------------------
// bf16x2-split MFMA GEMM (validated rounds 2-4):  C = act(A @ W^T + b1 + b2)
// ------------------------------------------------------------------------------
__device__ __forceinline__ void stage_tiles(const u16 (*L)[128][32],
    const u16* __restrict__ Ah, const u16* __restrict__ Al,
    const u16* __restrict__ Wh, const u16* __restrict__ Wl,
    int m0, int n0, int N, int K, int k0, int w, int l)
{
    const int srow = l >> 2, sslot = l & 3;
#pragma unroll
    for (int h = 0; h < 2; ++h) {
        const int rb = 32 * w + 16 * h;
        const int r = rb + srow;
        const int xr = (r >> 1) & 3;
        const int gk = k0 + ((sslot ^ xr) << 3);
        const size_t ao = (size_t)(m0 + r) * K + gk;
        int nrow = n0 + r; if (nrow >= N) nrow = N - 1;
        const size_t wo = (size_t)nrow * K + gk;
        gload16(Ah + ao, &L[0][rb][0]);
        gload16(Al + ao, &L[1][rb][0]);
        gload16(Wh + wo, &L[2][rb][0]);
        gload16(Wl + wo, &L[3][rb][0]);
    }
}

__global__ __launch_bounds__(256, 2) void gemm_mfma_split(
    const u16* __restrict__ Ah_, const u16* __restrict__ Al_,
    const u16* __restrict__ Wh_, const u16* __restrict__ Wl_,
    const float* __restrict__ b1, const float* __restrict__ b2,
    float* __restrict__ C, u16* __restrict__ CH, u16* __restrict__ CL,
    int M, int N, int K, int omode,
    long bsA, long bsW, int bsCrows, int cstride, int coff)
{
    __shared__ u16 lds[2][4][128][32];
    const int z = blockIdx.z;
    const u16* Ah = Ah_ + (size_t)z * bsA;
    const u16* Al = Al_ + (size_t)z * bsA;
    const u16* Wh = Wh_ + (size_t)z * bsW;
    const u16* Wl = Wl_ + (size_t)z * bsW;
    const int crow0 = z * bsCrows;
    const int tid = threadIdx.x;
    const int w = tid >> 6;
    const int l = tid & 63;
    const int m0 = blockIdx.y * 128;
    const int n0 = blockIdx.x * 128;
    const int wm = (w >> 1) * 64;
    const int wn = (w & 1) * 64;
    const int lr = l & 31;
    const int lk = l >> 5;

    f32x16_t acc[2][2];
#pragma unroll
    for (int si = 0; si < 2; ++si)
#pragma unroll
        for (int ni = 0; ni < 2; ++ni)
#pragma unroll
            for (int q = 0; q < 16; ++q) acc[si][ni][q] = 0.f;

    const int nk = K >> 5;
    stage_tiles(lds[0], Ah, Al, Wh, Wl, m0, n0, N, K, 0, w, l);
    __syncthreads();

    for (int t = 0; t < nk; ++t) {
        const int buf = t & 1;
        if (t + 1 < nk)
            stage_tiles(lds[buf ^ 1], Ah, Al, Wh, Wl, m0, n0, N, K, (t + 1) << 5, w, l);
        const u16 (*L)[128][32] = lds[buf];
#pragma unroll
        for (int kh = 0; kh < 2; ++kh) {
            const int k8 = lk + 2 * kh;
            bf16x8_t aH[2], aL[2], bH[2], bL[2];
#pragma unroll
            for (int si = 0; si < 2; ++si) {
                const int r = wm + si * 32 + lr;
                const int sl = (k8 ^ ((r >> 1) & 3)) << 3;
                aH[si] = *(const bf16x8_t*)&L[0][r][sl];
                aL[si] = *(const bf16x8_t*)&L[1][r][sl];
            }
#pragma unroll
            for (int ni = 0; ni < 2; ++ni) {
                const int r = wn + ni * 32 + lr;
                const int sl = (k8 ^ ((r >> 1) & 3)) << 3;
                bH[ni] = *(const bf16x8_t*)&L[2][r][sl];
                bL[ni] = *(const bf16x8_t*)&L[3][r][sl];
            }
#pragma unroll
            for (int si = 0; si < 2; ++si)
#pragma unroll
                for (int ni = 0; ni < 2; ++ni) {
                    acc[si][ni] = __builtin_amdgcn_mfma_f32_32x32x16_bf16(aH[si], bH[ni], acc[si][ni], 0, 0, 0);
                    acc[si][ni] = __builtin_amdgcn_mfma_f32_32x32x16_bf16(aH[si], bL[ni], acc[si][ni], 0, 0, 0);
                    acc[si][ni] = __builtin_amdgcn_mfma_f32_32x32x16_bf16(aL[si], bH[ni], acc[si][ni], 0, 0, 0);
                }
        }
        __syncthreads();
    }

    const int rbase = 4 * lk;
#pragma unroll
    for (int si = 0; si < 2; ++si)
#pragma unroll
        for (int ni = 0; ni < 2; ++ni) {
            const int n = n0 + wn + ni * 32 + lr;
            if (n >= N) continue;
            const float bias = (b1 ? b1[n] : 0.f) + (b2 ? b2[n] : 0.f);
#pragma unroll
            for (int q = 0; q < 16; ++q) {
                const int m = m0 + wm + si * 32 + (q & 3) + 8 * (q >> 2) + rbase;
                const int crow = crow0 + m;
                float x = acc[si][ni][q] + bias;
                if (omode == 0) {
                    C[(size_t)crow * N + n] = x;
                } else if (omode == 1) {
                    C[(size_t)crow * N + n] = tanhf(x);
                } else {
                    if (omode == 2) x = tanhf(x);
                    u16 h = f2bf(x);
                    CH[(size_t)crow * cstride + coff + n] = h;
                    CL[(size_t)crow * cstride + coff + n] = f2bf(x - bf2f(h));
                }
            }
        }
}

// ------------------------------------------------------------------------------
// Decoder GEMM (validated round 4): A = combH/L pre-split; W = etab fp32,
// split on the fly into swizzled LDS.
// ------------------------------------------------------------------------------
__global__ __launch_bounds__(256, 2) void gemm_dec(
    const u16* __restrict__ Ah, const u16* __restrict__ Al,
    const float* __restrict__ Wf, const float* __restrict__ b1,
    float* __restrict__ C, int M, int N, int K)
{
    __shared__ u16 lA[2][2][128][32];
    __shared__ u16 lB[2][2][128][32];
    const int tid = threadIdx.x;
    const int w = tid >> 6, l = tid & 63;
    const int m0 = blockIdx.y * 128, n0 = blockIdx.x * 128;
    const int wm = (w >> 1) * 64, wn = (w & 1) * 64;
    const int lr = l & 31, lk = l >> 5;
    const int srow = l >> 2, sslot = l & 3;

    f32x16_t acc[2][2];
#pragma unroll
    for (int si = 0; si < 2; ++si)
#pragma unroll
        for (int ni = 0; ni < 2; ++ni)
#pragma unroll
            for (int q = 0; q < 16; ++q) acc[si][ni][q] = 0.f;

    float4 br[4];

    auto loadB = [&](int k0) {
#pragma unroll
        for (int i = 0; i < 2; ++i) {
            const int c = tid * 2 + i;
            const int row = c >> 2, g = c & 3;
            int n = n0 + row; if (n >= N) n = N - 1;
            const float* s = Wf + (size_t)n * K + k0 + g * 8;
            br[2 * i]     = *(const float4*)s;
            br[2 * i + 1] = *(const float4*)(s + 4);
        }
    };
    auto writeB = [&](int buf) {
#pragma unroll
        for (int i = 0; i < 2; ++i) {
            const int c = tid * 2 + i;
            const int row = c >> 2, g = c & 3;
            const int gp = g ^ ((row >> 1) & 3);
            u16x8 H, L;
            const float* f = (const float*)&br[2 * i];
#pragma unroll
            for (int e = 0; e < 8; ++e) {
                u16 hh = f2bf(f[e]);
                H[e] = hh;
                L[e] = f2bf(f[e] - bf2f(hh));
            }
            *(u16x8*)&lB[buf][0][row][gp * 8] = H;
            *(u16x8*)&lB[buf][1][row][gp * 8] = L;
        }
    };
    auto stageA = [&](int buf, int k0) {
#pragma unroll
        for (int h = 0; h < 2; ++h) {
            const int rb = 32 * w + 16 * h;
            const int r = rb + srow;
            const int gk = k0 + ((sslot ^ ((r >> 1) & 3)) << 3);
            const size_t ao = (size_t)(m0 + r) * K + gk;
            gload16(Ah + ao, &lA[buf][0][rb][0]);
            gload16(Al + ao, &lA[buf][1][rb][0]);
        }
    };

    loadB(0);
    stageA(0, 0);
    writeB(0);
    __syncthreads();

    const int nk = K >> 5;
    for (int t = 0; t < nk; ++t) {
        const int buf = t & 1;
        if (t + 1 < nk) { loadB((t + 1) << 5); stageA(buf ^ 1, (t + 1) << 5); }
#pragma unroll
        for (int kh = 0; kh < 2; ++kh) {
            const int k8 = lk + 2 * kh;
            bf16x8_t aH[2], aL[2], bH[2], bL[2];
#pragma unroll
            for (int si = 0; si < 2; ++si) {
                const int r = wm + si * 32 + lr;
                const int sl = (k8 ^ ((r >> 1) & 3)) << 3;
                aH[si] = *(const bf16x8_t*)&lA[buf][0][r][sl];
                aL[si] = *(const bf16x8_t*)&lA[buf][1][r][sl];
            }
#pragma unroll
            for (int ni = 0; ni < 2; ++ni) {
                const int r = wn + ni * 32 + lr;
                const int sl = (k8 ^ ((r >> 1) & 3)) << 3;
                bH[ni] = *(const bf16x8_t*)&lB[buf][0][r][sl];
                bL[ni] = *(const bf16x8_t*)&lB[buf][1][r][sl];
            }
#pragma unroll
            for (int si = 0; si < 2; ++si)
#pragma unroll
                for (int ni = 0; ni < 2; ++ni) {
                    acc[si][ni] = __builtin_amdgcn_mfma_f32_32x32x16_bf16(aH[si], bH[ni], acc[si][ni], 0, 0, 0);
                    acc[si][ni] = __builtin_amdgcn_mfma_f32_32x32x16_bf16(aH[si], bL[ni], acc[si][ni], 0, 0, 0);
                    acc[si][ni] = __builtin_amdgcn_mfma_f32_32x32x16_bf16(aL[si], bH[ni], acc[si][ni], 0, 0, 0);
                }
        }
        if (t + 1 < nk) writeB(buf ^ 1);
        __syncthreads();
    }

    const int rbase = 4 * lk;
#pragma unroll
    for (int si = 0; si < 2; ++si)
#pragma unroll
        for (int ni = 0; ni < 2; ++ni) {
            const int n = n0 + wn + ni * 32 + lr;
            if (n >= N) continue;
            const float bias = b1 ? b1[n] : 0.f;
#pragma unroll
            for (int q = 0; q < 16; ++q) {
                const int m = m0 + wm + si * 32 + (q & 3) + 8 * (q >> 2) + rbase;
                C[(size_t)m * N + n] = acc[si][ni][q] + bias;
            }
        }
}

// ---------------------------------------------------- fp32 128x128 GEMM (Xp only)
__global__ __launch_bounds__(256, 2) void gemm128_wt(
    const float* __restrict__ A, const float* __restrict__ A2, int K1, int K,
    const float* __restrict__ W,
    const float* __restrict__ b1, const float* __restrict__ b2,
    float* __restrict__ C, int M, int N, int act) {
    __shared__ float As[16][132];
    __shared__ float Ws[16][132];
    const int tid = threadIdx.x;
    const int m0 = blockIdx.y * 128;
    const int n0 = blockIdx.x * 128;
    const int lr = tid >> 2;
    const int lc = (tid & 3) << 2;
    const int ty = tid >> 4;
    const int tx = tid & 15;
    float acc[2][2][4][4] = {{{{0.f}}}};
    for (int kc = 0; kc < K; kc += 16) {
        const int k = kc + lc;
#pragma unroll
        for (int h = 0; h < 2; ++h) {
            const int r = lr + 64 * h;
            float4 av;
            if (k < K1) av = *(const float4*)(A + (size_t)(m0 + r) * K1 + k);
            else        av = *(const float4*)(A2 + (size_t)(m0 + r) * (K - K1) + (k - K1));
            As[lc + 0][r] = av.x; As[lc + 1][r] = av.y;
            As[lc + 2][r] = av.z; As[lc + 3][r] = av.w;
            const int n = n0 + r;
            float4 wv = make_float4(0.f, 0.f, 0.f, 0.f);
            if (n < N) wv = *(const float4*)(W + (size_t)n * K + k);
            Ws[lc + 0][r] = wv.x; Ws[lc + 1][r] = wv.y;
            Ws[lc + 2][r] = wv.z; Ws[lc + 3][r] = wv.w;
        }
        __syncthreads();
#pragma unroll
        for (int kt = 0; kt < 16; ++kt) {
            float a[2][4], b[2][4];
            *(float4*)a[0] = *(const float4*)&As[kt][ty << 2];
            *(float4*)a[1] = *(const float4*)&As[kt][64 + (ty << 2)];
            *(float4*)b[0] = *(const float4*)&Ws[kt][tx << 2];
            *(float4*)b[1] = *(const float4*)&Ws[kt][64 + (tx << 2)];
#pragma unroll
            for (int rg = 0; rg < 2; ++rg)
#pragma unroll
                for (int cg = 0; cg < 2; ++cg)
#pragma unroll
                    for (int i = 0; i < 4; ++i)
#pragma unroll
                        for (int j = 0; j < 4; ++j)
                            acc[rg][cg][i][j] = fmaf(a[rg][i], b[cg][j], acc[rg][cg][i][j]);
        }
        __syncthreads();
    }
#pragma unroll
    for (int rg = 0; rg < 2; ++rg)
#pragma unroll
    for (int i = 0; i < 4; ++i) {
        const int m = m0 + rg * 64 + (ty << 2) + i;
#pragma unroll
        for (int cg = 0; cg < 2; ++cg) {
            const int nbase = n0 + cg * 64 + (tx << 2);
            float4 v;
            float* vp = (float*)&v;
#pragma unroll
            for (int j = 0; j < 4; ++j) {
                int n = nbase + j;
                float x = acc[rg][cg][i][j];
                if (n < N) {
                    if (b1) x += b1[n];
                    if (b2) x += b2[n];
                    if (act == 1) x = tanhf(x);
                }
                vp[j] = x;
            }
            if (nbase + 3 < N) {
                *(float4*)(C + (size_t)m * N + nbase) = v;
            } else {
                for (int j = 0; j < 4; ++j)
                    if (nbase + j < N) C[(size_t)m * N + nbase + j] = vp[j];
            }
        }
    }
}

// ------------------------------------------------------------------------------
// Persistent encoder LSTM: 128 blocks x 256 threads, one launch for all 512 steps.
// Block owns 4 j's (16 gate rows, LDS-resident Whh).  h staged to LDS per step in
// two 256-k halves.  c held in registers.  Software grid barrier (agent-scope
// atomics + fences; 128 blocks x <=75KB LDS -> all resident under any packing).
// Thread map: wave = k-quarter, lane: o=lane>>2 (row 0..15: jr=o>>2,g=o&3),
// bg = lane&3 (b-group of 8).
// ------------------------------------------------------------------------------
__global__ __launch_bounds__(256) void enc_persist_k(
    const float* __restrict__ Xg, const float* __restrict__ Whh,
    float* __restrict__ enc, unsigned* __restrict__ bar)
{
    __shared__ float wlds[16][520];
    __shared__ float hlds[32][264];
    __shared__ float pw[4][16][4][8];
    const int tid = threadIdx.x;
    const int wave = tid >> 6;
    const int lane = tid & 63;
    const int o = lane >> 2;
    const int bg = lane & 3;
    const int j0 = blockIdx.x * 4;

    // Whh rows -> LDS once: row o -> Whh[(o&3)*512 + j0 + (o>>2)]
#pragma unroll
    for (int p = 0; p < 8; ++p) {
        int f4 = tid + p * 256;                  // 0..2047 (16 rows x 128 f4)
        int ro = f4 >> 7, kq = (f4 & 127) << 2;
        float4 v = *(const float4*)(Whh + (size_t)((ro & 3) * 512 + j0 + (ro >> 2)) * Hz + kq);
        *(float4*)&wlds[ro][kq] = v;
    }
    float c_reg = 0.f;                           // tid<128: (b=tid&31, jr=tid>>5)
    __syncthreads();

    for (int t = 0; t < Tz; ++t) {
        // prefetch xg for finalize threads (hidden under compute)
        float xv0 = 0.f, xv1 = 0.f, xv2 = 0.f, xv3 = 0.f;
        if (tid < 128) {
            const int b = tid & 31, jr = tid >> 5;
            const float* xg = Xg + ((size_t)b * Tz + t) * 2048 + j0 + jr;
            xv0 = xg[0]; xv1 = xg[512]; xv2 = xg[1024]; xv3 = xg[1536];
        }

        float acc[8];
#pragma unroll
        for (int i = 0; i < 8; ++i) acc[i] = 0.f;

        if (t > 0) {
#pragma unroll
            for (int hf = 0; hf < 2; ++hf) {
                // stage half (32KB) coalesced, bg-XOR-swizzled k-slots
                float4 tmp[8];
#pragma unroll
                for (int p = 0; p < 8; ++p) {
                    int f4 = tid + p * 256;              // 0..2047 (32 b x 64 f4)
                    int b = f4 >> 6, s = f4 & 63;
                    tmp[p] = *(const float4*)(enc + ((size_t)b * Tz + (t - 1)) * Hz + hf * 256 + (s << 2));
                }
#pragma unroll
                for (int p = 0; p < 8; ++p) {
                    int f4 = tid + p * 256;
                    int b = f4 >> 6, s = f4 & 63;
                    *(float4*)&hlds[b][(s ^ ((b >> 3) & 3)) << 2] = tmp[p];
                }
                __syncthreads();
                // compute: row o, b = bg*8+i, k = wave*64 + it*4 (within half)
#pragma unroll 4
                for (int it = 0; it < 16; ++it) {
                    const int s = wave * 16 + it;
                    const int kf = s << 2;
                    float4 w4 = *(const float4*)&wlds[o][hf * 256 + kf];
#pragma unroll
                    for (int i = 0; i < 8; ++i) {
                        const int b = bg * 8 + i;
                        float4 h4 = *(const float4*)&hlds[b][(s ^ bg) << 2];
                        acc[i] += w4.x * h4.x + w4.y * h4.y + w4.z * h4.z + w4.w * h4.w;
                    }
                }
                __syncthreads();
            }
        }
        // partial write + reduce
        *(float4*)&pw[wave][o][bg][0] = make_float4(acc[0], acc[1], acc[2], acc[3]);
        *(float4*)&pw[wave][o][bg][4] = make_float4(acc[4], acc[5], acc[6], acc[7]);
        __syncthreads();

        if (tid < 128) {
            const int b = tid & 31, jr = tid >> 5;
            const int bh = b >> 3, bl = b & 7;
            float g0 = 0.f, g1 = 0.f, g2 = 0.f, g3 = 0.f;
#pragma unroll
            for (int w2 = 0; w2 < 4; ++w2) {
                g0 += pw[w2][jr * 4 + 0][bh][bl];
                g1 += pw[w2][jr * 4 + 1][bh][bl];
                g2 += pw[w2][jr * 4 + 2][bh][bl];
                g3 += pw[w2][jr * 4 + 3][bh][bl];
            }
            g0 += xv0; g1 += xv1; g2 += xv2; g3 += xv3;
            float ig = sigf(g0), fg = sigf(g1), gg = tanhf(g2), og = sigf(g3);
            c_reg = fg * c_reg + ig * gg;
            float hn = og * tanhf(c_reg);
            enc[((size_t)b * Tz + t) * Hz + j0 + jr] = hn;
        }
        __threadfence();
        __syncthreads();
        if (t < Tz - 1) {
            if (tid == 0) {
                __hip_atomic_fetch_add(bar, 1u, __ATOMIC_RELEASE, __HIP_MEMORY_SCOPE_AGENT);
                const unsigned target = (unsigned)NBLK * (t + 1);
                while (__hip_atomic_load(bar, __ATOMIC_ACQUIRE, __HIP_MEMORY_SCOPE_AGENT) < target)
                    __builtin_amdgcn_s_sleep(8);
            }
            __syncthreads();
        }
    }
}

__global__ void init_bar_k(unsigned* bar) { *bar = 0u; }

// ---------------------------- positional LSTM + mu_w/sig + mu scan (single block)
__global__ __launch_bounds__(640) void pos_k(const float* __restrict__ Xp,
                                             const float* __restrict__ Wphh,
                                             const float* __restrict__ Wmu,
                                             const float* __restrict__ bmu,
                                             const float* __restrict__ Wsig,
                                             const float* __restrict__ bsig,
                                             float* __restrict__ muv,
                                             float* __restrict__ sgv) {
    __shared__ float hs[Bz][Pz];
    __shared__ float ws[80][Pz];
    __shared__ float mw[Bz][4];
    __shared__ float muprev[Bz];
    __shared__ float wmu_s[4][Pz];
    const int tid = threadIdx.x;
    for (int i = tid; i < 80 * Pz; i += 640) ws[i / Pz][i % Pz] = Wphh[i];
    for (int i = tid; i < 3 * Pz; i += 640) wmu_s[i / Pz][i % Pz] = Wmu[i];
    if (tid < Pz) wmu_s[3][tid] = Wsig[tid];
    if (tid < Bz) muprev[tid] = 0.f;
    const int b = tid / Pz;
    const int p = tid % Pz;
    float c_r = 0.f;
    hs[b][p] = 0.f;
    __syncthreads();
    for (int t = 0; t < Tz; ++t) {
        const float* xp = Xp + ((size_t)b * Tz + t) * 80;
        float a0 = xp[p], a1 = xp[20 + p], a2 = xp[40 + p], a3 = xp[60 + p];
#pragma unroll
        for (int k = 0; k < Pz; ++k) {
            float hk = hs[b][k];
            a0 += ws[p][k] * hk;
            a1 += ws[20 + p][k] * hk;
            a2 += ws[40 + p][k] * hk;
            a3 += ws[60 + p][k] * hk;
        }
        float ig = sigf(a0), fg = sigf(a1), gg = tanhf(a2), og = sigf(a3);
        c_r = fg * c_r + ig * gg;
        float hn = og * tanhf(c_r);
        __syncthreads();
        hs[b][p] = hn;
        __syncthreads();
        if (tid < 128) {
            int bb = tid >> 2, o = tid & 3;
            float s = (o < 3) ? bmu[o] : bsig[0];
#pragma unroll
            for (int k = 0; k < Pz; ++k) s += wmu_s[o][k] * hs[bb][k];
            mw[bb][o] = s;
        }
        __syncthreads();
        if (tid < Bz) {
            float w0 = fmaxf(mw[tid][0], 0.f);
            float w1 = fmaxf(mw[tid][1], 0.f);
            float w2 = fmaxf(mw[tid][2], 0.f);
            float m = w0 * muprev[tid] + w1 * (1.f / 512.f) + w2 * (t + 1.f) / 512.f;
            muprev[tid] = m;
            muv[tid * Tz + t] = m;
            sgv[tid * Tz + t] = sigf(mw[tid][3]);
        }
        __syncthreads();
    }
}

// ---------------------- attention weights, L2-normalized rows, split bf16 output
__global__ __launch_bounds__(256) void attw_k(const float* __restrict__ muv,
                                              const float* __restrict__ sgv,
                                              u16* __restrict__ wH,
                                              u16* __restrict__ wL) {
    const int row = blockIdx.x * 4 + (threadIdx.x >> 6);
    const int lane = threadIdx.x & 63;
    const int b = row >> 9, j = row & 511;
    const float m = muv[b * Tz + j];
    const float s = sgv[b * Tz + j];
    const float inv = 0.5f / (s * s);
    const float rj = 1.0f / (j + 1.0f);
    float vals[8];
    float ss = 0.f;
#pragma unroll
    for (int i = 0; i < 8; ++i) {
        int t = lane + i * 64;
        float v = 0.f;
        if (t <= j) {
            float d = t * rj - m;
            v = expf(-d * d * inv);
        }
        vals[i] = v;
        ss += v * v;
    }
    for (int off = 32; off; off >>= 1) ss += __shfl_xor(ss, off);
    float nrm = 1.0f / fmaxf(sqrtf(ss), 1e-12f);
    u16* rH = wH + (size_t)row * Tz;
    u16* rL = wL + (size_t)row * Tz;
#pragma unroll
    for (int i = 0; i < 8; ++i) {
        float v = vals[i] * nrm;
        u16 h = f2bf(v);
        rH[lane + i * 64] = h;
        rL[lane + i * 64] = f2bf(v - bf2f(h));
    }
}

// ---------------------------------------------------------------------------------
extern "C" void kernel_launch(void* const* d_in, const int* in_sizes, int n_in,
                              void* d_out, int out_size, void* d_ws, size_t ws_size,
                              hipStream_t stream) {
    const int*   inp      = (const int*)d_in[0];
    const float* etab     = (const float*)d_in[3];
    const float* dec_bias = (const float*)d_in[4];
    const float* W_ih     = (const float*)d_in[5];
    const float* W_hh     = (const float*)d_in[6];
    const float* b_ih     = (const float*)d_in[7];
    const float* b_hh     = (const float*)d_in[8];
    const float* Wp_ih    = (const float*)d_in[9];
    const float* Wp_hh    = (const float*)d_in[10];
    const float* bp_ih    = (const float*)d_in[11];
    const float* bp_hh    = (const float*)d_in[12];
    const float* W_mu     = (const float*)d_in[13];
    const float* b_mu     = (const float*)d_in[14];
    const float* W_sig    = (const float*)d_in[15];
    const float* b_sig    = (const float*)d_in[16];
    const float* W_cat    = (const float*)d_in[17];
    const float* b_cat    = (const float*)d_in[18];

    float* out = (float*)d_out;
    // All transients inside d_out (163.84M floats); dead before decoder rewrite.
    float*    Xg    = out;                          // 33,554,432 f
    float*    enc   = out + 33554432;               //  8,388,608
    unsigned* bar   = (unsigned*)(out + 41943040);  //  barrier counter (old cbuf slot)
    float*    Xp    = out + 41959424;               //  1,310,720
    float*    muv   = out + 43270144;               //     16,384
    float*    sgv   = out + 43286528;               //     16,384
    u16*  embH   = (u16*)(out + 43302912);          // 16384x512
    u16*  embL   = (u16*)(out + 47497216);
    u16*  WihH   = (u16*)(out + 51691520);          // 2048x512
    u16*  WihL   = (u16*)(out + 52215808);
    u16*  WcatH  = (u16*)(out + 52740096);          // 512x1024
    u16*  WcatL  = (u16*)(out + 53002240);
    u16*  catH   = (u16*)(out + 53264384);          // 16384x1024
    u16*  catL   = (u16*)(out + 61652992);
    u16*  attwH  = (u16*)(out + 70041600);          // 32x512x512
    u16*  attwL  = (u16*)(out + 74235904);
    u16*  encTH  = (u16*)(out + 78430208);          // 32x512x512
    u16*  encTL  = (u16*)(out + 82624512);          // end 86,818,816 < 163,840,000

    u16* combH = (u16*)d_ws;                        // 16384x512 u16
    u16* combL = (u16*)((char*)d_ws + 16777216);    // 33,554,432 B total (proven)

    // 1. splits + barrier init
    init_bar_k<<<1, 1, 0, stream>>>(bar);
    embed_split_k<<<8192, 256, 0, stream>>>(inp, etab, embH, embL);
    split_k<<<1024, 256, 0, stream>>>(W_ih, WihH, WihL, 2048 * 128, 128, 512, 0);
    split_k<<<512, 256, 0, stream>>>(W_cat, WcatH, WcatL, 512 * 256, 256, 1024, 0);

    // 2. Xg = emb @ W_ih^T + b_ih + b_hh  (MFMA split, fp32 out)
    gemm_mfma_split<<<dim3(16, 128), 256, 0, stream>>>(
        embH, embL, WihH, WihL, b_ih, b_hh, Xg, nullptr, nullptr,
        16384, 2048, 512, 0, 0, 0, 0, 0, 0);

    // 3. encoder recurrence — ONE persistent launch, software grid barrier
    enc_persist_k<<<NBLK, 256, 0, stream>>>(Xg, W_hh, enc, bar);

    // 4. enc -> cat cols [512,1024); enc -> encT H/L
    split_k<<<8192, 256, 0, stream>>>(enc, catH, catL, 16384 * 128, 128, 1024, 512);
    tsplit_k<<<dim3(8, 8, 32), 256, 0, stream>>>(enc, encTH, encTL);

    // 5. Xp = enc @ Wp_ih^T + biases (fp32, N=80)
    gemm128_wt<<<dim3(1, 128), 256, 0, stream>>>(enc, nullptr, 512, 512, Wp_ih, bp_ih, bp_hh,
                                                 Xp, 16384, 80, 0);
    // 6. positional LSTM + heads + mu scan
    pos_k<<<1, 640, 0, stream>>>(Xp, Wp_hh, W_mu, b_mu, W_sig, b_sig, muv, sgv);
    // 7. attention weights -> bf16 split
    attw_k<<<4096, 256, 0, stream>>>(muv, sgv, attwH, attwL);

    // 8. ctx = attw @ encT^T (batched MFMA) -> cat cols [0,512) split bf16
    gemm_mfma_split<<<dim3(4, 4, 32), 256, 0, stream>>>(
        attwH, attwL, encTH, encTL, nullptr, nullptr, nullptr, catH, catL,
        512, 512, 512, 3, (long)512 * 512, (long)512 * 512, 512, 1024, 0);

    // 9. comb = tanh(cat @ W_cat^T + b_cat) -> split bf16 into ws
    gemm_mfma_split<<<dim3(4, 128), 256, 0, stream>>>(
        catH, catL, WcatH, WcatL, b_cat, nullptr, nullptr, combH, combL,
        16384, 512, 1024, 2, 0, 0, 0, 512, 0);

    // 10. decoded = comb @ embedding^T + dec_bias
    gemm_dec<<<dim3(79, 128), 256, 0, stream>>>(
        combH, combL, etab, dec_bias, out, 16384, 10000, 512);
}

// Round 6
// 8532.646 us; speedup vs baseline: 1.6767x; 1.6767x over previous
//
#include <hip/hip_runtime.h>
#include <math.h>

#define Vz 10000
#define Bz 32
#define Tz 512
#define Hz 512
#define Pz 20

typedef unsigned short u16;
typedef unsigned long long u64;
typedef __attribute__((ext_vector_type(8)))  short bf16x8_t;   // 8 bf16 = 4 VGPR
typedef __attribute__((ext_vector_type(8)))  unsigned short u16x8;
typedef __attribute__((ext_vector_type(16))) float f32x16_t;   // 32x32 acc frag

__device__ __forceinline__ float sigf(float x) { return 1.0f / (1.0f + expf(-x)); }

__device__ __forceinline__ u16 f2bf(float x) {           // round-to-nearest-even
    unsigned u = __float_as_uint(x);
    u += 0x7fff + ((u >> 16) & 1);
    return (u16)(u >> 16);
}
__device__ __forceinline__ float bf2f(u16 h) {
    return __uint_as_float(((unsigned)h) << 16);
}

__device__ __forceinline__ void gload16(const u16* g, const u16* l) {
    __builtin_amdgcn_global_load_lds(
        (const __attribute__((address_space(1))) void*)g,
        (__attribute__((address_space(3))) void*)l, 16, 0, 0);
}

// ---------------------------------------------------------------- splitters
__global__ __launch_bounds__(256) void split_k(const float* __restrict__ src,
                                               u16* __restrict__ dH, u16* __restrict__ dL,
                                               int total4, int srcW4, int dstStride, int colOff) {
    int i = blockIdx.x * 256 + threadIdx.x;
    if (i >= total4) return;
    int row = i / srcW4;
    int c4 = (i - row * srcW4) << 2;
    float4 v = *(const float4*)(src + (size_t)row * ((size_t)srcW4 << 2) + c4);
    ushort4 H, L;
    H.x = f2bf(v.x); L.x = f2bf(v.x - bf2f(H.x));
    H.y = f2bf(v.y); L.y = f2bf(v.y - bf2f(H.y));
    H.z = f2bf(v.z); L.z = f2bf(v.z - bf2f(H.z));
    H.w = f2bf(v.w); L.w = f2bf(v.w - bf2f(H.w));
    size_t d = (size_t)row * dstStride + colOff + c4;
    *(ushort4*)(dH + d) = H;
    *(ushort4*)(dL + d) = L;
}

__global__ __launch_bounds__(256) void embed_split_k(const int* __restrict__ inp,
                                                     const float* __restrict__ etab,
                                                     u16* __restrict__ dH, u16* __restrict__ dL) {
    int i = blockIdx.x * 256 + threadIdx.x;
    int row = i >> 7;
    int c4 = (i & 127) << 2;
    float4 v = *(const float4*)(etab + (size_t)inp[row] * Hz + c4);
    ushort4 H, L;
    H.x = f2bf(v.x); L.x = f2bf(v.x - bf2f(H.x));
    H.y = f2bf(v.y); L.y = f2bf(v.y - bf2f(H.y));
    H.z = f2bf(v.z); L.z = f2bf(v.z - bf2f(H.z));
    H.w = f2bf(v.w); L.w = f2bf(v.w - bf2f(H.w));
    size_t d = (size_t)row * Hz + c4;
    *(ushort4*)(dH + d) = H;
    *(ushort4*)(dL + d) = L;
}

// per-batch transpose + split: enc[b][t][h] -> encT H/L [b][h][t]
__global__ __launch_bounds__(256) void tsplit_k(const float* __restrict__ enc,
                                                u16* __restrict__ dH, u16* __restrict__ dL) {
    __shared__ float ls[64][65];
    const int b = blockIdx.z;
    const int t0 = blockIdx.y * 64;
    const int h0 = blockIdx.x * 64;
    const int tid = threadIdx.x;
    const int rr = tid >> 4;
    const int cc = (tid & 15) << 2;
    const float* eb = enc + (size_t)b * Tz * Hz;
#pragma unroll
    for (int i = 0; i < 4; ++i) {
        int t = rr + i * 16;
        float4 v = *(const float4*)(eb + (size_t)(t0 + t) * Hz + h0 + cc);
        ls[t][cc] = v.x; ls[t][cc + 1] = v.y; ls[t][cc + 2] = v.z; ls[t][cc + 3] = v.w;
    }
    __syncthreads();
    u16* oH = dH + (size_t)b * Tz * Hz;
    u16* oL = dL + (size_t)b * Tz * Hz;
#pragma unroll
    for (int i = 0; i < 4; ++i) {
        int h = rr + i * 16;
        float x0 = ls[cc + 0][h], x1 = ls[cc + 1][h], x2 = ls[cc + 2][h], x3 = ls[cc + 3][h];
        ushort4 H, L;
        H.x = f2bf(x0); L.x = f2bf(x0 - bf2f(H.x));
        H.y = f2bf(x1); L.y = f2bf(x1 - bf2f(H.y));
        H.z = f2bf(x2); L.z = f2bf(x2 - bf2f(H.z));
        H.w = f2bf(x3); L.w = f2bf(x3 - bf2f(H.w));
        size_t d = (size_t)(h0 + h) * Tz + t0 + cc;
        *(ushort4*)(oH + d) = H;
        *(ushort4*)(oL + d) = L;
    }
}

// ------------------------------------------------------------------------------
// bf16x2-split MFMA GEMM (validated rounds 2-5):  C = act(A @ W^T + b1 + b2)
// ------------------------------------------------------------------------------
__device__ __forceinline__ void stage_tiles(const u16 (*L)[128][32],
    const u16* __restrict__ Ah, const u16* __restrict__ Al,
    const u16* __restrict__ Wh, const u16* __restrict__ Wl,
    int m0, int n0, int N, int K, int k0, int w, int l)
{
    const int srow = l >> 2, sslot = l & 3;
#pragma unroll
    for (int h = 0; h < 2; ++h) {
        const int rb = 32 * w + 16 * h;
        const int r = rb + srow;
        const int xr = (r >> 1) & 3;
        const int gk = k0 + ((sslot ^ xr) << 3);
        const size_t ao = (size_t)(m0 + r) * K + gk;
        int nrow = n0 + r; if (nrow >= N) nrow = N - 1;
        const size_t wo = (size_t)nrow * K + gk;
        gload16(Ah + ao, &L[0][rb][0]);
        gload16(Al + ao, &L[1][rb][0]);
        gload16(Wh + wo, &L[2][rb][0]);
        gload16(Wl + wo, &L[3][rb][0]);
    }
}

__global__ __launch_bounds__(256, 2) void gemm_mfma_split(
    const u16* __restrict__ Ah_, const u16* __restrict__ Al_,
    const u16* __restrict__ Wh_, const u16* __restrict__ Wl_,
    const float* __restrict__ b1, const float* __restrict__ b2,
    float* __restrict__ C, u16* __restrict__ CH, u16* __restrict__ CL,
    int M, int N, int K, int omode,
    long bsA, long bsW, int bsCrows, int cstride, int coff)
{
    __shared__ u16 lds[2][4][128][32];
    const int z = blockIdx.z;
    const u16* Ah = Ah_ + (size_t)z * bsA;
    const u16* Al = Al_ + (size_t)z * bsA;
    const u16* Wh = Wh_ + (size_t)z * bsW;
    const u16* Wl = Wl_ + (size_t)z * bsW;
    const int crow0 = z * bsCrows;
    const int tid = threadIdx.x;
    const int w = tid >> 6;
    const int l = tid & 63;
    const int m0 = blockIdx.y * 128;
    const int n0 = blockIdx.x * 128;
    const int wm = (w >> 1) * 64;
    const int wn = (w & 1) * 64;
    const int lr = l & 31;
    const int lk = l >> 5;

    f32x16_t acc[2][2];
#pragma unroll
    for (int si = 0; si < 2; ++si)
#pragma unroll
        for (int ni = 0; ni < 2; ++ni)
#pragma unroll
            for (int q = 0; q < 16; ++q) acc[si][ni][q] = 0.f;

    const int nk = K >> 5;
    stage_tiles(lds[0], Ah, Al, Wh, Wl, m0, n0, N, K, 0, w, l);
    __syncthreads();

    for (int t = 0; t < nk; ++t) {
        const int buf = t & 1;
        if (t + 1 < nk)
            stage_tiles(lds[buf ^ 1], Ah, Al, Wh, Wl, m0, n0, N, K, (t + 1) << 5, w, l);
        const u16 (*L)[128][32] = lds[buf];
#pragma unroll
        for (int kh = 0; kh < 2; ++kh) {
            const int k8 = lk + 2 * kh;
            bf16x8_t aH[2], aL[2], bH[2], bL[2];
#pragma unroll
            for (int si = 0; si < 2; ++si) {
                const int r = wm + si * 32 + lr;
                const int sl = (k8 ^ ((r >> 1) & 3)) << 3;
                aH[si] = *(const bf16x8_t*)&L[0][r][sl];
                aL[si] = *(const bf16x8_t*)&L[1][r][sl];
            }
#pragma unroll
            for (int ni = 0; ni < 2; ++ni) {
                const int r = wn + ni * 32 + lr;
                const int sl = (k8 ^ ((r >> 1) & 3)) << 3;
                bH[ni] = *(const bf16x8_t*)&L[2][r][sl];
                bL[ni] = *(const bf16x8_t*)&L[3][r][sl];
            }
#pragma unroll
            for (int si = 0; si < 2; ++si)
#pragma unroll
                for (int ni = 0; ni < 2; ++ni) {
                    acc[si][ni] = __builtin_amdgcn_mfma_f32_32x32x16_bf16(aH[si], bH[ni], acc[si][ni], 0, 0, 0);
                    acc[si][ni] = __builtin_amdgcn_mfma_f32_32x32x16_bf16(aH[si], bL[ni], acc[si][ni], 0, 0, 0);
                    acc[si][ni] = __builtin_amdgcn_mfma_f32_32x32x16_bf16(aL[si], bH[ni], acc[si][ni], 0, 0, 0);
                }
        }
        __syncthreads();
    }

    const int rbase = 4 * lk;
#pragma unroll
    for (int si = 0; si < 2; ++si)
#pragma unroll
        for (int ni = 0; ni < 2; ++ni) {
            const int n = n0 + wn + ni * 32 + lr;
            if (n >= N) continue;
            const float bias = (b1 ? b1[n] : 0.f) + (b2 ? b2[n] : 0.f);
#pragma unroll
            for (int q = 0; q < 16; ++q) {
                const int m = m0 + wm + si * 32 + (q & 3) + 8 * (q >> 2) + rbase;
                const int crow = crow0 + m;
                float x = acc[si][ni][q] + bias;
                if (omode == 0) {
                    C[(size_t)crow * N + n] = x;
                } else if (omode == 1) {
                    C[(size_t)crow * N + n] = tanhf(x);
                } else {
                    if (omode == 2) x = tanhf(x);
                    u16 h = f2bf(x);
                    CH[(size_t)crow * cstride + coff + n] = h;
                    CL[(size_t)crow * cstride + coff + n] = f2bf(x - bf2f(h));
                }
            }
        }
}

// ------------------------------------------------------------------------------
// Decoder GEMM (validated round 4): A = combH/L pre-split; W = etab fp32,
// split on the fly into swizzled LDS.
// ------------------------------------------------------------------------------
__global__ __launch_bounds__(256, 2) void gemm_dec(
    const u16* __restrict__ Ah, const u16* __restrict__ Al,
    const float* __restrict__ Wf, const float* __restrict__ b1,
    float* __restrict__ C, int M, int N, int K)
{
    __shared__ u16 lA[2][2][128][32];
    __shared__ u16 lB[2][2][128][32];
    const int tid = threadIdx.x;
    const int w = tid >> 6, l = tid & 63;
    const int m0 = blockIdx.y * 128, n0 = blockIdx.x * 128;
    const int wm = (w >> 1) * 64, wn = (w & 1) * 64;
    const int lr = l & 31, lk = l >> 5;
    const int srow = l >> 2, sslot = l & 3;

    f32x16_t acc[2][2];
#pragma unroll
    for (int si = 0; si < 2; ++si)
#pragma unroll
        for (int ni = 0; ni < 2; ++ni)
#pragma unroll
            for (int q = 0; q < 16; ++q) acc[si][ni][q] = 0.f;

    float4 br[4];

    auto loadB = [&](int k0) {
#pragma unroll
        for (int i = 0; i < 2; ++i) {
            const int c = tid * 2 + i;
            const int row = c >> 2, g = c & 3;
            int n = n0 + row; if (n >= N) n = N - 1;
            const float* s = Wf + (size_t)n * K + k0 + g * 8;
            br[2 * i]     = *(const float4*)s;
            br[2 * i + 1] = *(const float4*)(s + 4);
        }
    };
    auto writeB = [&](int buf) {
#pragma unroll
        for (int i = 0; i < 2; ++i) {
            const int c = tid * 2 + i;
            const int row = c >> 2, g = c & 3;
            const int gp = g ^ ((row >> 1) & 3);
            u16x8 H, L;
            const float* f = (const float*)&br[2 * i];
#pragma unroll
            for (int e = 0; e < 8; ++e) {
                u16 hh = f2bf(f[e]);
                H[e] = hh;
                L[e] = f2bf(f[e] - bf2f(hh));
            }
            *(u16x8*)&lB[buf][0][row][gp * 8] = H;
            *(u16x8*)&lB[buf][1][row][gp * 8] = L;
        }
    };
    auto stageA = [&](int buf, int k0) {
#pragma unroll
        for (int h = 0; h < 2; ++h) {
            const int rb = 32 * w + 16 * h;
            const int r = rb + srow;
            const int gk = k0 + ((sslot ^ ((r >> 1) & 3)) << 3);
            const size_t ao = (size_t)(m0 + r) * K + gk;
            gload16(Ah + ao, &lA[buf][0][rb][0]);
            gload16(Al + ao, &lA[buf][1][rb][0]);
        }
    };

    loadB(0);
    stageA(0, 0);
    writeB(0);
    __syncthreads();

    const int nk = K >> 5;
    for (int t = 0; t < nk; ++t) {
        const int buf = t & 1;
        if (t + 1 < nk) { loadB((t + 1) << 5); stageA(buf ^ 1, (t + 1) << 5); }
#pragma unroll
        for (int kh = 0; kh < 2; ++kh) {
            const int k8 = lk + 2 * kh;
            bf16x8_t aH[2], aL[2], bH[2], bL[2];
#pragma unroll
            for (int si = 0; si < 2; ++si) {
                const int r = wm + si * 32 + lr;
                const int sl = (k8 ^ ((r >> 1) & 3)) << 3;
                aH[si] = *(const bf16x8_t*)&lA[buf][0][r][sl];
                aL[si] = *(const bf16x8_t*)&lA[buf][1][r][sl];
            }
#pragma unroll
            for (int ni = 0; ni < 2; ++ni) {
                const int r = wn + ni * 32 + lr;
                const int sl = (k8 ^ ((r >> 1) & 3)) << 3;
                bH[ni] = *(const bf16x8_t*)&lB[buf][0][r][sl];
                bL[ni] = *(const bf16x8_t*)&lB[buf][1][r][sl];
            }
#pragma unroll
            for (int si = 0; si < 2; ++si)
#pragma unroll
                for (int ni = 0; ni < 2; ++ni) {
                    acc[si][ni] = __builtin_amdgcn_mfma_f32_32x32x16_bf16(aH[si], bH[ni], acc[si][ni], 0, 0, 0);
                    acc[si][ni] = __builtin_amdgcn_mfma_f32_32x32x16_bf16(aH[si], bL[ni], acc[si][ni], 0, 0, 0);
                    acc[si][ni] = __builtin_amdgcn_mfma_f32_32x32x16_bf16(aL[si], bH[ni], acc[si][ni], 0, 0, 0);
                }
        }
        if (t + 1 < nk) writeB(buf ^ 1);
        __syncthreads();
    }

    const int rbase = 4 * lk;
#pragma unroll
    for (int si = 0; si < 2; ++si)
#pragma unroll
        for (int ni = 0; ni < 2; ++ni) {
            const int n = n0 + wn + ni * 32 + lr;
            if (n >= N) continue;
            const float bias = b1 ? b1[n] : 0.f;
#pragma unroll
            for (int q = 0; q < 16; ++q) {
                const int m = m0 + wm + si * 32 + (q & 3) + 8 * (q >> 2) + rbase;
                C[(size_t)m * N + n] = acc[si][ni][q] + bias;
            }
        }
}

// ---------------------------------------------------- fp32 128x128 GEMM (Xp only)
__global__ __launch_bounds__(256, 2) void gemm128_wt(
    const float* __restrict__ A, const float* __restrict__ A2, int K1, int K,
    const float* __restrict__ W,
    const float* __restrict__ b1, const float* __restrict__ b2,
    float* __restrict__ C, int M, int N, int act) {
    __shared__ float As[16][132];
    __shared__ float Ws[16][132];
    const int tid = threadIdx.x;
    const int m0 = blockIdx.y * 128;
    const int n0 = blockIdx.x * 128;
    const int lr = tid >> 2;
    const int lc = (tid & 3) << 2;
    const int ty = tid >> 4;
    const int tx = tid & 15;
    float acc[2][2][4][4] = {{{{0.f}}}};
    for (int kc = 0; kc < K; kc += 16) {
        const int k = kc + lc;
#pragma unroll
        for (int h = 0; h < 2; ++h) {
            const int r = lr + 64 * h;
            float4 av;
            if (k < K1) av = *(const float4*)(A + (size_t)(m0 + r) * K1 + k);
            else        av = *(const float4*)(A2 + (size_t)(m0 + r) * (K - K1) + (k - K1));
            As[lc + 0][r] = av.x; As[lc + 1][r] = av.y;
            As[lc + 2][r] = av.z; As[lc + 3][r] = av.w;
            const int n = n0 + r;
            float4 wv = make_float4(0.f, 0.f, 0.f, 0.f);
            if (n < N) wv = *(const float4*)(W + (size_t)n * K + k);
            Ws[lc + 0][r] = wv.x; Ws[lc + 1][r] = wv.y;
            Ws[lc + 2][r] = wv.z; Ws[lc + 3][r] = wv.w;
        }
        __syncthreads();
#pragma unroll
        for (int kt = 0; kt < 16; ++kt) {
            float a[2][4], b[2][4];
            *(float4*)a[0] = *(const float4*)&As[kt][ty << 2];
            *(float4*)a[1] = *(const float4*)&As[kt][64 + (ty << 2)];
            *(float4*)b[0] = *(const float4*)&Ws[kt][tx << 2];
            *(float4*)b[1] = *(const float4*)&Ws[kt][64 + (tx << 2)];
#pragma unroll
            for (int rg = 0; rg < 2; ++rg)
#pragma unroll
                for (int cg = 0; cg < 2; ++cg)
#pragma unroll
                    for (int i = 0; i < 4; ++i)
#pragma unroll
                        for (int j = 0; j < 4; ++j)
                            acc[rg][cg][i][j] = fmaf(a[rg][i], b[cg][j], acc[rg][cg][i][j]);
        }
        __syncthreads();
    }
#pragma unroll
    for (int rg = 0; rg < 2; ++rg)
#pragma unroll
    for (int i = 0; i < 4; ++i) {
        const int m = m0 + rg * 64 + (ty << 2) + i;
#pragma unroll
        for (int cg = 0; cg < 2; ++cg) {
            const int nbase = n0 + cg * 64 + (tx << 2);
            float4 v;
            float* vp = (float*)&v;
#pragma unroll
            for (int j = 0; j < 4; ++j) {
                int n = nbase + j;
                float x = acc[rg][cg][i][j];
                if (n < N) {
                    if (b1) x += b1[n];
                    if (b2) x += b2[n];
                    if (act == 1) x = tanhf(x);
                }
                vp[j] = x;
            }
            if (nbase + 3 < N) {
                *(float4*)(C + (size_t)m * N + nbase) = v;
            } else {
                for (int j = 0; j < 4; ++j)
                    if (nbase + j < N) C[(size_t)m * N + nbase + j] = vp[j];
            }
        }
    }
}

// ------------------------------------------------------------------------------
// Persistent encoder LSTM v2: 128 blocks = 4 batch-groups x 32 j-slices.
// Block = (group g: 8 batches, slice s: 16 j = 64 Whh rows).  NO global barrier:
// sync only among the 32 blocks of a group, via per-block FLAG ARRAY (monotonic
// step counters, no RMW contention).  h exchanged through L3 with relaxed
// agent-scope loads/stores (L2 bypass) so the per-block Whh slice (128 KB)
// stays hot in its XCD L2 across all 512 steps.  c in registers.
// Thread map: tid = q*8 + bb; q in [0,32): jj = q&15, gp = q>>4 (gate pair).
// Thread computes gates {2gp, 2gp+1} for (bb, jj).  tid<128 finalizes (gp=0
// thread pairs with tid+128).
// ------------------------------------------------------------------------------
__global__ __launch_bounds__(256) void enc_persist_k(
    const float* __restrict__ Xg, const float* __restrict__ Whh,
    float* __restrict__ enc, unsigned* __restrict__ flags)
{
    __shared__ float hlds[8][516];     // 8 batches x 512 (+4 pad) = 16.5 KB
    __shared__ float ex[128][2];       // upper gate-pair exchange
    const int tid = threadIdx.x;
    const int g = blockIdx.x >> 5;     // batch group
    const int sidx = blockIdx.x & 31;  // j-slice
    const int j0 = sidx * 16;
    const int bb = tid & 7;            // batch within group
    const int q = tid >> 3;            // 0..31
    const int jj = q & 15;
    const int gp = q >> 4;             // 0: gates i,f   1: gates g,o
    const float* Wr0 = Whh + (size_t)((2 * gp) * 512 + j0 + jj) * Hz;
    const float* Wr1 = Wr0 + (size_t)512 * Hz;
    unsigned* myflag = flags + blockIdx.x * 16;          // 64B padded
    float c_reg = 0.f;                 // tid<128: cell state for (g*8+bb, j0+jj)

    for (int t = 0; t < Tz; ++t) {
        // xg prefetch (independent of h)
        float xv0 = 0.f, xv1 = 0.f, xv2 = 0.f, xv3 = 0.f;
        if (tid < 128) {
            const float* xp = Xg + ((size_t)(g * 8 + bb) * Tz + t) * 2048 + j0 + jj;
            xv0 = xp[0]; xv1 = xp[512]; xv2 = xp[1024]; xv3 = xp[1536];
        }

        float acc0 = 0.f, acc1 = 0.f;
        if (t > 0) {
            // wait for the 32 blocks of this group to finish step t-1
            if (tid < 32) {
                const unsigned* p = flags + (g * 32 + tid) * 16;
                int it = 0;
                while (__hip_atomic_load(p, __ATOMIC_RELAXED, __HIP_MEMORY_SCOPE_AGENT) < (unsigned)t) {
                    __builtin_amdgcn_s_sleep(2);
                    if (++it > (1 << 20)) {     // safety: acquire-load fallback
                        while (__hip_atomic_load(p, __ATOMIC_ACQUIRE, __HIP_MEMORY_SCOPE_AGENT) < (unsigned)t)
                            __builtin_amdgcn_s_sleep(16);
                        break;
                    }
                }
            }
            __syncthreads();
            // stage h[t-1] (8 batches x 512) from L3 (relaxed agent = L2 bypass)
#pragma unroll
            for (int p = 0; p < 8; ++p) {
                const int wi = tid + p * 256;            // u64 word 0..2047
                const int hb = wi >> 8, off = wi & 255;
                u64 v = __hip_atomic_load(
                    (const u64*)(enc + ((size_t)(g * 8 + hb) * Tz + (t - 1)) * Hz) + off,
                    __ATOMIC_RELAXED, __HIP_MEMORY_SCOPE_AGENT);
                *(u64*)&hlds[hb][off * 2] = v;
            }
            __syncthreads();
            // dot products: 2 rows x 512 k
#pragma unroll 8
            for (int k = 0; k < Hz; k += 4) {
                float4 w0 = *(const float4*)(Wr0 + k);
                float4 w1 = *(const float4*)(Wr1 + k);
                float4 h4 = *(const float4*)&hlds[bb][k];
                acc0 += w0.x * h4.x + w0.y * h4.y + w0.z * h4.z + w0.w * h4.w;
                acc1 += w1.x * h4.x + w1.y * h4.y + w1.z * h4.z + w1.w * h4.w;
            }
        }
        // exchange upper gate pair, finalize
        if (tid >= 128) { ex[tid - 128][0] = acc0; ex[tid - 128][1] = acc1; }
        __syncthreads();
        if (tid < 128) {
            float gi = acc0 + xv0;
            float gf = acc1 + xv1;
            float gg = ex[tid][0] + xv2;
            float go = ex[tid][1] + xv3;
            float ig = sigf(gi), fg = sigf(gf), G = tanhf(gg), og = sigf(go);
            c_reg = fg * c_reg + ig * G;
            float hn = og * tanhf(c_reg);
            __hip_atomic_store(enc + ((size_t)(g * 8 + bb) * Tz + t) * Hz + j0 + jj, hn,
                               __ATOMIC_RELAXED, __HIP_MEMORY_SCOPE_AGENT);
        }
        __syncthreads();   // drains each thread's stores (vmcnt) before flag
        if (t + 1 < Tz && tid == 0)
            __hip_atomic_store(myflag, (unsigned)(t + 1),
                               __ATOMIC_RELEASE, __HIP_MEMORY_SCOPE_AGENT);
    }
}

__global__ __launch_bounds__(256) void init_flags_k(unsigned* flags) {
    int i = blockIdx.x * 256 + threadIdx.x;
    if (i < 128 * 16) flags[i] = 0u;
}

// ---------------------------- positional LSTM + mu_w/sig + mu scan (single block)
__global__ __launch_bounds__(640) void pos_k(const float* __restrict__ Xp,
                                             const float* __restrict__ Wphh,
                                             const float* __restrict__ Wmu,
                                             const float* __restrict__ bmu,
                                             const float* __restrict__ Wsig,
                                             const float* __restrict__ bsig,
                                             float* __restrict__ muv,
                                             float* __restrict__ sgv) {
    __shared__ float hs[Bz][Pz];
    __shared__ float ws[80][Pz];
    __shared__ float mw[Bz][4];
    __shared__ float muprev[Bz];
    __shared__ float wmu_s[4][Pz];
    const int tid = threadIdx.x;
    for (int i = tid; i < 80 * Pz; i += 640) ws[i / Pz][i % Pz] = Wphh[i];
    for (int i = tid; i < 3 * Pz; i += 640) wmu_s[i / Pz][i % Pz] = Wmu[i];
    if (tid < Pz) wmu_s[3][tid] = Wsig[tid];
    if (tid < Bz) muprev[tid] = 0.f;
    const int b = tid / Pz;
    const int p = tid % Pz;
    float c_r = 0.f;
    hs[b][p] = 0.f;
    __syncthreads();
    for (int t = 0; t < Tz; ++t) {
        const float* xp = Xp + ((size_t)b * Tz + t) * 80;
        float a0 = xp[p], a1 = xp[20 + p], a2 = xp[40 + p], a3 = xp[60 + p];
#pragma unroll
        for (int k = 0; k < Pz; ++k) {
            float hk = hs[b][k];
            a0 += ws[p][k] * hk;
            a1 += ws[20 + p][k] * hk;
            a2 += ws[40 + p][k] * hk;
            a3 += ws[60 + p][k] * hk;
        }
        float ig = sigf(a0), fg = sigf(a1), gg = tanhf(a2), og = sigf(a3);
        c_r = fg * c_r + ig * gg;
        float hn = og * tanhf(c_r);
        __syncthreads();
        hs[b][p] = hn;
        __syncthreads();
        if (tid < 128) {
            int bb = tid >> 2, o = tid & 3;
            float s = (o < 3) ? bmu[o] : bsig[0];
#pragma unroll
            for (int k = 0; k < Pz; ++k) s += wmu_s[o][k] * hs[bb][k];
            mw[bb][o] = s;
        }
        __syncthreads();
        if (tid < Bz) {
            float w0 = fmaxf(mw[tid][0], 0.f);
            float w1 = fmaxf(mw[tid][1], 0.f);
            float w2 = fmaxf(mw[tid][2], 0.f);
            float m = w0 * muprev[tid] + w1 * (1.f / 512.f) + w2 * (t + 1.f) / 512.f;
            muprev[tid] = m;
            muv[tid * Tz + t] = m;
            sgv[tid * Tz + t] = sigf(mw[tid][3]);
        }
        __syncthreads();
    }
}

// ---------------------- attention weights, L2-normalized rows, split bf16 output
__global__ __launch_bounds__(256) void attw_k(const float* __restrict__ muv,
                                              const float* __restrict__ sgv,
                                              u16* __restrict__ wH,
                                              u16* __restrict__ wL) {
    const int row = blockIdx.x * 4 + (threadIdx.x >> 6);
    const int lane = threadIdx.x & 63;
    const int b = row >> 9, j = row & 511;
    const float m = muv[b * Tz + j];
    const float s = sgv[b * Tz + j];
    const float inv = 0.5f / (s * s);
    const float rj = 1.0f / (j + 1.0f);
    float vals[8];
    float ss = 0.f;
#pragma unroll
    for (int i = 0; i < 8; ++i) {
        int t = lane + i * 64;
        float v = 0.f;
        if (t <= j) {
            float d = t * rj - m;
            v = expf(-d * d * inv);
        }
        vals[i] = v;
        ss += v * v;
    }
    for (int off = 32; off; off >>= 1) ss += __shfl_xor(ss, off);
    float nrm = 1.0f / fmaxf(sqrtf(ss), 1e-12f);
    u16* rH = wH + (size_t)row * Tz;
    u16* rL = wL + (size_t)row * Tz;
#pragma unroll
    for (int i = 0; i < 8; ++i) {
        float v = vals[i] * nrm;
        u16 h = f2bf(v);
        rH[lane + i * 64] = h;
        rL[lane + i * 64] = f2bf(v - bf2f(h));
    }
}

// ---------------------------------------------------------------------------------
extern "C" void kernel_launch(void* const* d_in, const int* in_sizes, int n_in,
                              void* d_out, int out_size, void* d_ws, size_t ws_size,
                              hipStream_t stream) {
    const int*   inp      = (const int*)d_in[0];
    const float* etab     = (const float*)d_in[3];
    const float* dec_bias = (const float*)d_in[4];
    const float* W_ih     = (const float*)d_in[5];
    const float* W_hh     = (const float*)d_in[6];
    const float* b_ih     = (const float*)d_in[7];
    const float* b_hh     = (const float*)d_in[8];
    const float* Wp_ih    = (const float*)d_in[9];
    const float* Wp_hh    = (const float*)d_in[10];
    const float* bp_ih    = (const float*)d_in[11];
    const float* bp_hh    = (const float*)d_in[12];
    const float* W_mu     = (const float*)d_in[13];
    const float* b_mu     = (const float*)d_in[14];
    const float* W_sig    = (const float*)d_in[15];
    const float* b_sig    = (const float*)d_in[16];
    const float* W_cat    = (const float*)d_in[17];
    const float* b_cat    = (const float*)d_in[18];

    float* out = (float*)d_out;
    // All transients inside d_out (163.84M floats); dead before decoder rewrite.
    float*    Xg    = out;                          // 33,554,432 f
    float*    enc   = out + 33554432;               //  8,388,608
    unsigned* flags = (unsigned*)(out + 41943040);  //  128 x 16 u32 (64B padded)
    float*    Xp    = out + 41959424;               //  1,310,720
    float*    muv   = out + 43270144;               //     16,384
    float*    sgv   = out + 43286528;               //     16,384
    u16*  embH   = (u16*)(out + 43302912);          // 16384x512
    u16*  embL   = (u16*)(out + 47497216);
    u16*  WihH   = (u16*)(out + 51691520);          // 2048x512
    u16*  WihL   = (u16*)(out + 52215808);
    u16*  WcatH  = (u16*)(out + 52740096);          // 512x1024
    u16*  WcatL  = (u16*)(out + 53002240);
    u16*  catH   = (u16*)(out + 53264384);          // 16384x1024
    u16*  catL   = (u16*)(out + 61652992);
    u16*  attwH  = (u16*)(out + 70041600);          // 32x512x512
    u16*  attwL  = (u16*)(out + 74235904);
    u16*  encTH  = (u16*)(out + 78430208);          // 32x512x512
    u16*  encTL  = (u16*)(out + 82624512);          // end 86,818,816 < 163,840,000

    u16* combH = (u16*)d_ws;                        // 16384x512 u16
    u16* combL = (u16*)((char*)d_ws + 16777216);    // 33,554,432 B total (proven)

    // 1. splits + flag init
    init_flags_k<<<8, 256, 0, stream>>>(flags);
    embed_split_k<<<8192, 256, 0, stream>>>(inp, etab, embH, embL);
    split_k<<<1024, 256, 0, stream>>>(W_ih, WihH, WihL, 2048 * 128, 128, 512, 0);
    split_k<<<512, 256, 0, stream>>>(W_cat, WcatH, WcatL, 512 * 256, 256, 1024, 0);

    // 2. Xg = emb @ W_ih^T + b_ih + b_hh  (MFMA split, fp32 out)
    gemm_mfma_split<<<dim3(16, 128), 256, 0, stream>>>(
        embH, embL, WihH, WihL, b_ih, b_hh, Xg, nullptr, nullptr,
        16384, 2048, 512, 0, 0, 0, 0, 0, 0);

    // 3. encoder recurrence — persistent, batch-group x j-slice, flag-array sync
    enc_persist_k<<<128, 256, 0, stream>>>(Xg, W_hh, enc, flags);

    // 4. enc -> cat cols [512,1024); enc -> encT H/L
    split_k<<<8192, 256, 0, stream>>>(enc, catH, catL, 16384 * 128, 128, 1024, 512);
    tsplit_k<<<dim3(8, 8, 32), 256, 0, stream>>>(enc, encTH, encTL);

    // 5. Xp = enc @ Wp_ih^T + biases (fp32, N=80)
    gemm128_wt<<<dim3(1, 128), 256, 0, stream>>>(enc, nullptr, 512, 512, Wp_ih, bp_ih, bp_hh,
                                                 Xp, 16384, 80, 0);
    // 6. positional LSTM + heads + mu scan
    pos_k<<<1, 640, 0, stream>>>(Xp, Wp_hh, W_mu, b_mu, W_sig, b_sig, muv, sgv);
    // 7. attention weights -> bf16 split
    attw_k<<<4096, 256, 0, stream>>>(muv, sgv, attwH, attwL);

    // 8. ctx = attw @ encT^T (batched MFMA) -> cat cols [0,512) split bf16
    gemm_mfma_split<<<dim3(4, 4, 32), 256, 0, stream>>>(
        attwH, attwL, encTH, encTL, nullptr, nullptr, nullptr, catH, catL,
        512, 512, 512, 3, (long)512 * 512, (long)512 * 512, 512, 1024, 0);

    // 9. comb = tanh(cat @ W_cat^T + b_cat) -> split bf16 into ws
    gemm_mfma_split<<<dim3(4, 128), 256, 0, stream>>>(
        catH, catL, WcatH, WcatL, b_cat, nullptr, nullptr, combH, combL,
        16384, 512, 1024, 2, 0, 0, 0, 512, 0);

    // 10. decoded = comb @ embedding^T + dec_bias
    gemm_dec<<<dim3(79, 128), 256, 0, stream>>>(
        combH, combL, etab, dec_bias, out, 16384, 10000, 512);
}